// Round 9
// baseline (461.528 us; speedup 1.0000x reference)
//
#include <hip/hip_runtime.h>
#include <hip/hip_bf16.h>
#include <stdint.h>

typedef __hip_bfloat16 bf16;
typedef __bf16 bf16x8 __attribute__((ext_vector_type(8)));
typedef float f32x4 __attribute__((ext_vector_type(4)));

#define NB 1024
#define NM 4096
#define NZ 64
#define NH 8192

__device__ __forceinline__ float bf2f(bf16 x) { return __bfloat162float(x); }
__device__ __forceinline__ bf16 f2bf(float x) { return __float2bfloat16(x); }
__device__ __forceinline__ float sigf(float x) { return 1.f / (1.f + __expf(-x)); }

// fp32 x -> bf16 (4 elements/thread)
__global__ __launch_bounds__(256) void cvt_f32_bf16(const float* __restrict__ src,
                                                    bf16* __restrict__ dst, int n4) {
  const int i = blockIdx.x * 256 + threadIdx.x;
  if (i >= n4) return;
  const float4 v = ((const float4*)src)[i];
  bf16 o[4] = {f2bf(v.x), f2bf(v.y), f2bf(v.z), f2bf(v.w)};
  *(short4*)&dst[i * 4] = *(short4*)o;
}

__global__ void zero_f32(float* p, int n) {
  int i = blockIdx.x * blockDim.x + threadIdx.x;
  if (i < n) p[i] = 0.f;
}

// concat mu/lv weights -> wcat fp32 [128][4096] (dead d_out range, pre-dec)
__global__ __launch_bounds__(256) void wcat_build(const float* __restrict__ muw,
                                                  const float* __restrict__ lvw,
                                                  float* __restrict__ wcat) {
  const int v = blockIdx.x * 256 + threadIdx.x;   // 0..131071 float4-ids
  const int j = v >> 10;                          // row 0..127
  const int k4 = v & 1023;                        // float4 within row
  const float* src = (j < 64) ? (muw + (size_t)j * NM) : (lvw + (size_t)(j - 64) * NM);
  ((float4*)(wcat + (size_t)j * NM))[k4] = ((const float4*)src)[k4];
}

#define VMW6 asm volatile("s_waitcnt vmcnt(6)" ::: "memory")
#define VMW4 asm volatile("s_waitcnt vmcnt(4)" ::: "memory")
#define VMW0 asm volatile("s_waitcnt vmcnt(0)" ::: "memory")
#define LGKM0 asm volatile("s_waitcnt lgkmcnt(0)" ::: "memory")

// ---------------------------------------------------------------------------
// MFMA NT GEMM v6: C[r,c] = relu( sum_k A[r,k]*W[c,k] + bias[c] )
// 64x64 tile, 4 waves (256 thr), wave -> 32x32. 40KB LDS -> 4 blocks/CU =
// 4 INDEPENDENT barrier groups (r8: doubling waves in the SAME group bought
// only 10%; independent streams are what hides the drain). Grid 16x64 = 1024.
// Counted-vmcnt pipeline: 6 VMEM/thread/tile (4 W-f4 + 2 A-gload_lds),
// VMW6 drains exactly tile i with i+1,i+2 in flight. A slots mod-3, W mod-2.
// LDS XOR-swizzle throughout (conflicts==0 since r1).
// ---------------------------------------------------------------------------
__global__ __launch_bounds__(256) void gemm_nt(const bf16* __restrict__ A,
                                               const float* __restrict__ W,
                                               const float* __restrict__ bias,
                                               bf16* __restrict__ C,
                                               int K, int N) {
  __shared__ __attribute__((aligned(16))) bf16 smA[3][64 * 64];  // 24 KB
  __shared__ __attribute__((aligned(16))) bf16 smB[2][64 * 64];  // 16 KB
  const int tid  = threadIdx.x;
  const int lane = tid & 63;
  const int w    = tid >> 6;   // 0..3
  const int wr   = w >> 1;     // 0..1 : 32-row group
  const int wc   = w & 1;      // 0..1 : 32-col group

  // XCD-bijective swizzle (1024 blocks, gridDim.x == 16)
  const int lid  = blockIdx.y * 16 + blockIdx.x;   // 0..1023
  const int wgid = (lid & 7) * 128 + (lid >> 3);   // per-XCD contiguous chunk
  const int row0 = (wgid & 15) * 64;
  const int col0 = (wgid >> 4) * 64;

  f32x4 acc[2][2];
#pragma unroll
  for (int i = 0; i < 2; i++)
#pragma unroll
    for (int j = 0; j < 2; j++) acc[i][j] = (f32x4){0.f, 0.f, 0.f, 0.f};

  // W staging: thread -> smB row tid>>2, k elems [(tid&3)*16, +16)
  const int swr = tid >> 2;          // 0..63
  const int swk = (tid & 3) * 16;
  const float* wp = W + (size_t)(col0 + swr) * K + swk;
  const int swz = (swr & 7) << 3;
  const int woff0 = swr * 64 + ((swk + 0) ^ swz);
  const int woff1 = swr * 64 + ((swk + 8) ^ swz);

  auto load_W = [&](float4 (&wv)[4], int kk) {
    wv[0] = *(const float4*)(wp + kk);
    wv[1] = *(const float4*)(wp + kk + 4);
    wv[2] = *(const float4*)(wp + kk + 8);
    wv[3] = *(const float4*)(wp + kk + 12);
  };

  auto stage_A = [&](int slot, int kk) {
#pragma unroll
    for (int q = 0; q < 2; q++) {
      const int chunk = q * 256 + w * 64 + lane;   // 0..511
      const int r  = chunk >> 3;                   // 0..63
      const int ke = ((chunk & 7) ^ (r & 7)) * 8;
      __builtin_amdgcn_global_load_lds(
          (__attribute__((address_space(1))) unsigned int*)(A + (size_t)(row0 + r) * K + (kk + ke)),
          (__attribute__((address_space(3))) unsigned int*)(&smA[slot][(q * 256 + w * 64) * 8]),
          16, 0, 0);
    }
  };

  auto write_W = [&](int slot, const float4 (&wv)[4]) {
    bf16 t[16] = {f2bf(wv[0].x), f2bf(wv[0].y), f2bf(wv[0].z), f2bf(wv[0].w),
                  f2bf(wv[1].x), f2bf(wv[1].y), f2bf(wv[1].z), f2bf(wv[1].w),
                  f2bf(wv[2].x), f2bf(wv[2].y), f2bf(wv[2].z), f2bf(wv[2].w),
                  f2bf(wv[3].x), f2bf(wv[3].y), f2bf(wv[3].z), f2bf(wv[3].w)};
    *(bf16x8*)&smB[slot][woff0] = ((bf16x8*)t)[0];
    *(bf16x8*)&smB[slot][woff1] = ((bf16x8*)t)[1];
  };

  auto compute = [&](int sa, int ws) {
#pragma unroll
    for (int ks = 0; ks < 64; ks += 32) {
      const int kq = ks + (lane >> 4) * 8;
      bf16x8 af[2], bfr[2];
#pragma unroll
      for (int i = 0; i < 2; i++) {
        const int r = wr * 32 + i * 16 + (lane & 15);
        af[i] = *(const bf16x8*)&smA[sa][r * 64 + (kq ^ ((r & 7) << 3))];
      }
#pragma unroll
      for (int j = 0; j < 2; j++) {
        const int r = wc * 32 + j * 16 + (lane & 15);
        bfr[j] = *(const bf16x8*)&smB[ws][r * 64 + (kq ^ ((r & 7) << 3))];
      }
#pragma unroll
      for (int i = 0; i < 2; i++)
#pragma unroll
        for (int j = 0; j < 2; j++)
          acc[i][j] = __builtin_amdgcn_mfma_f32_16x16x32_bf16(af[i], bfr[j], acc[i][j], 0, 0, 0);
    }
  };

  const int K64 = K >> 6;   // even, >= 4
  float4 wA[4], wB[4];

  load_W(wA, 0);
  stage_A(0, 0);
  asm volatile("" ::: "memory");
  load_W(wB, 64);
  stage_A(1, 64);

  int sa = 0;
  for (int i = 0; i + 2 < K64; i += 2) {
    const int nx  = (sa + 1 == 3) ? 0 : sa + 1;
    const int nnx = (nx + 1 == 3) ? 0 : nx + 1;
    VMW6;
    write_W(0, wA);
    LGKM0;
    __builtin_amdgcn_s_barrier();
    __builtin_amdgcn_sched_barrier(0);
    load_W(wA, (i + 2) * 64);
    stage_A(nnx, (i + 2) * 64);
    compute(sa, 0);
    VMW6;
    write_W(1, wB);
    LGKM0;
    __builtin_amdgcn_s_barrier();
    __builtin_amdgcn_sched_barrier(0);
    load_W(wB, (i + 3) * 64);
    stage_A(sa, (i + 3) * 64);
    compute(nx, 1);
    sa = nnx;
  }
  VMW6;
  write_W(0, wA);
  LGKM0;
  __builtin_amdgcn_s_barrier();
  __builtin_amdgcn_sched_barrier(0);
  compute(sa, 0);
  VMW0;
  write_W(1, wB);
  LGKM0;
  __builtin_amdgcn_s_barrier();
  __builtin_amdgcn_sched_barrier(0);
  compute((sa + 1 == 3) ? 0 : sa + 1, 1);

  // C/D layout: col = lane&15, row = (lane>>4)*4 + t   [m89-verified]
#pragma unroll
  for (int i = 0; i < 2; i++) {
#pragma unroll
    for (int j = 0; j < 2; j++) {
      const int cc = col0 + wc * 32 + j * 16 + (lane & 15);
      const float bs = bias[cc];
#pragma unroll
      for (int t = 0; t < 4; t++) {
        const int rr = row0 + wr * 32 + i * 16 + (lane >> 4) * 4 + t;
        float v = acc[i][j][t] + bs;
        v = v > 0.f ? v : 0.f;   // relu (both encoder layers)
        C[(size_t)rr * N + cc] = f2bf(v);
      }
    }
  }
}

// ---------------------------------------------------------------------------
// mu/logvar as MFMA split-K: C[1024x128] = h2 @ wcat^T, split K=4096 into 16
// chunks of 256 (K64=4), atomic fp32 accumulate into zpre. Structure = the
// r8-verified 512-thr counted-vmcnt pipeline (tile 128x64, 4 VMEM/thr/tile).
// grid (8, 2, 16) = 256 blocks. No bias/relu (zfin applies bias).
// ---------------------------------------------------------------------------
__global__ __launch_bounds__(512) void mulv_mfma(const bf16* __restrict__ A,
                                                 const float* __restrict__ Wc,
                                                 float* __restrict__ zpre) {
  __shared__ __attribute__((aligned(16))) bf16 smA[3][128 * 64];  // 48 KB
  __shared__ __attribute__((aligned(16))) bf16 smB[2][64 * 64];   // 16 KB
  const int tid  = threadIdx.x;
  const int lane = tid & 63;
  const int w    = tid >> 6;   // 0..7
  const int wr   = w >> 1;     // 0..3
  const int wc   = w & 1;      // 0..1
  const int row0 = blockIdx.x * 128;
  const int col0 = blockIdx.y * 64;
  const int k0g  = blockIdx.z * 256;

  f32x4 acc[2][2];
#pragma unroll
  for (int i = 0; i < 2; i++)
#pragma unroll
    for (int j = 0; j < 2; j++) acc[i][j] = (f32x4){0.f, 0.f, 0.f, 0.f};

  const int swr = tid >> 3;          // 0..63
  const int swk = (tid & 7) * 8;     // 0..56
  const float* wp = Wc + (size_t)(col0 + swr) * NM + k0g + swk;
  const int woff = swr * 64 + (swk ^ ((swr & 7) << 3));

  auto load_W = [&](float4 (&wv)[2], int kk) {
    wv[0] = *(const float4*)(wp + kk);
    wv[1] = *(const float4*)(wp + kk + 4);
  };

  auto stage_A = [&](int slot, int kk) {
#pragma unroll
    for (int q = 0; q < 2; q++) {
      const int chunk = q * 512 + w * 64 + lane;   // 0..1023
      const int r  = chunk >> 3;                   // 0..127
      const int ke = ((chunk & 7) ^ (r & 7)) * 8;
      __builtin_amdgcn_global_load_lds(
          (__attribute__((address_space(1))) unsigned int*)(A + (size_t)(row0 + r) * NM + (k0g + kk + ke)),
          (__attribute__((address_space(3))) unsigned int*)(&smA[slot][(q * 512 + w * 64) * 8]),
          16, 0, 0);
    }
  };

  auto write_W = [&](int slot, const float4 (&wv)[2]) {
    bf16 t[8] = {f2bf(wv[0].x), f2bf(wv[0].y), f2bf(wv[0].z), f2bf(wv[0].w),
                 f2bf(wv[1].x), f2bf(wv[1].y), f2bf(wv[1].z), f2bf(wv[1].w)};
    *(bf16x8*)&smB[slot][woff] = *(bf16x8*)t;
  };

  auto compute = [&](int sa, int ws) {
#pragma unroll
    for (int ks = 0; ks < 64; ks += 32) {
      const int kq = ks + (lane >> 4) * 8;
      bf16x8 af[2], bfr[2];
#pragma unroll
      for (int i = 0; i < 2; i++) {
        const int r = wr * 32 + i * 16 + (lane & 15);
        af[i] = *(const bf16x8*)&smA[sa][r * 64 + (kq ^ ((r & 7) << 3))];
      }
#pragma unroll
      for (int j = 0; j < 2; j++) {
        const int r = wc * 32 + j * 16 + (lane & 15);
        bfr[j] = *(const bf16x8*)&smB[ws][r * 64 + (kq ^ ((r & 7) << 3))];
      }
#pragma unroll
      for (int i = 0; i < 2; i++)
#pragma unroll
        for (int j = 0; j < 2; j++)
          acc[i][j] = __builtin_amdgcn_mfma_f32_16x16x32_bf16(af[i], bfr[j], acc[i][j], 0, 0, 0);
    }
  };

  float4 wA[2], wB[2];
  load_W(wA, 0);
  stage_A(0, 0);
  asm volatile("" ::: "memory");
  load_W(wB, 64);
  stage_A(1, 64);

  // K64 = 4: one loop iteration (tiles 0,1) + peels (tiles 2,3)
  int sa = 0;
  {
    VMW4;
    write_W(0, wA);
    LGKM0;
    __builtin_amdgcn_s_barrier();
    __builtin_amdgcn_sched_barrier(0);
    load_W(wA, 128);
    stage_A(2, 128);
    compute(0, 0);
    VMW4;
    write_W(1, wB);
    LGKM0;
    __builtin_amdgcn_s_barrier();
    __builtin_amdgcn_sched_barrier(0);
    load_W(wB, 192);
    stage_A(0, 192);
    compute(1, 1);
    sa = 2;
  }
  VMW4;
  write_W(0, wA);
  LGKM0;
  __builtin_amdgcn_s_barrier();
  __builtin_amdgcn_sched_barrier(0);
  compute(2, 0);
  VMW0;
  write_W(1, wB);
  LGKM0;
  __builtin_amdgcn_s_barrier();
  __builtin_amdgcn_sched_barrier(0);
  compute(0, 1);

  // atomic split-K epilogue (zpre pre-zeroed)
#pragma unroll
  for (int i = 0; i < 2; i++) {
#pragma unroll
    for (int j = 0; j < 2; j++) {
      const int cc = col0 + wc * 32 + j * 16 + (lane & 15);
#pragma unroll
      for (int t = 0; t < 4; t++) {
        const int rr = row0 + wr * 32 + i * 16 + (lane >> 4) * 4 + t;
        atomicAdd(&zpre[(size_t)rr * 128 + cc], acc[i][j][t]);
      }
    }
  }
}

// mu/lv bias + reparameterization; fp32 outputs, fp32 z (ws)
__global__ void zfin(const float* __restrict__ zpre, const float* __restrict__ eps,
                     const float* __restrict__ mub, const float* __restrict__ lvb,
                     float* __restrict__ out_mu, float* __restrict__ out_lv,
                     float* __restrict__ z) {
  const int i = blockIdx.x * 256 + threadIdx.x;   // B*Z = 65536
  const int b = i >> 6, j = i & 63;
  const float mu = zpre[(size_t)b * 128 + j] + mub[j];
  const float lv = zpre[(size_t)b * 128 + 64 + j] + lvb[j];
  const float zz = mu + expf(0.5f * lv) * eps[i];
  out_mu[i] = mu;
  out_lv[i] = lv;
  z[i] = zz;
}

// ---------------------------------------------------------------------------
// Fused decoder branch v4 (unchanged from r8): two-half fw staging, 34.3KB
// LDS -> 4 blocks/CU; m-pair x 8b per thread. grid (16,16,4).
// ---------------------------------------------------------------------------
__global__ __launch_bounds__(256) void dec_fused(
    const float* __restrict__ z,
    const float* __restrict__ fw, const float* __restrict__ fb,
    const float* __restrict__ hw, const float* __restrict__ hb,
    const float* __restrict__ ow, const float* __restrict__ ob,
    float* __restrict__ out) {
  __shared__ __attribute__((aligned(16))) float sZ[64][68];   // 17.4 KB
  __shared__ __attribute__((aligned(16))) float sFW[32][132]; // 16.9 KB
  const int tid = threadIdx.x;
  const int b0 = blockIdx.x * 64;
  const int m0 = blockIdx.y * 256;
  const int mi = blockIdx.z;          // 0..3 : 64-m group
  {
    const int r  = tid >> 2;          // b-row 0..63
    const int c0 = (tid & 3) * 16;    // k-chunk
    const float* p = z + (size_t)(b0 + r) * NZ + c0;
#pragma unroll
    for (int i = 0; i < 16; i++) sZ[c0 + i][r] = p[i];
  }

  const int bq = tid >> 5;   // 0..7 : 8-batch group
  const int tm = tid & 31;   // 0..31 : m-pair index
  const int mb = m0 + mi * 64;
  const int mA = mb + 2 * tm;   // even; thread covers m in {mA, mA+1}

  const float4 fb4 = *(const float4*)&fb[2 * mA];   // {A0,A1,B0,B1}
  float aA0[8], aA1[8], aB0[8], aB1[8];
#pragma unroll
  for (int j = 0; j < 8; j++) { aA0[j] = fb4.x; aA1[j] = fb4.y; aB0[j] = fb4.z; aB1[j] = fb4.w; }

  const int R0 = 2 * mb;
#pragma unroll
  for (int kh = 0; kh < 2; kh++) {
    __syncthreads();   // prev-half compute done (kh=0: harmless)
    {
#pragma unroll
      for (int q = 0; q < 4; q++) {
        const int v = tid + q * 256;        // 0..1023 float4-ids
        const int grow = v >> 3;            // 0..127
        const int gk = (v & 7) * 4;         // 0..28
        const float4 f4 = *(const float4*)&fw[(size_t)(R0 + grow) * NZ + kh * 32 + gk];
        sFW[gk + 0][grow] = f4.x;
        sFW[gk + 1][grow] = f4.y;
        sFW[gk + 2][grow] = f4.z;
        sFW[gk + 3][grow] = f4.w;
      }
    }
    __syncthreads();   // sFW half (and, at kh=0, sZ) visible

#pragma unroll 8
    for (int k2 = 0; k2 < 32; k2++) {
      const int k = kh * 32 + k2;
      const float4 w4 = *(const float4*)&sFW[k2][4 * tm];
      const float4 z0 = *(const float4*)&sZ[k][bq * 8 + 0];
      const float4 z1 = *(const float4*)&sZ[k][bq * 8 + 4];
      const float zv[8] = {z0.x, z0.y, z0.z, z0.w, z1.x, z1.y, z1.z, z1.w};
#pragma unroll
      for (int j = 0; j < 8; j++) {
        aA0[j] += zv[j] * w4.x;
        aA1[j] += zv[j] * w4.y;
        aB0[j] += zv[j] * w4.z;
        aB1[j] += zv[j] * w4.w;
      }
    }
  }

  float4 hwA[2], hwB[2], hb4[2];
#pragma unroll
  for (int l = 0; l < 2; l++) {
    hwA[l] = *(const float4*)&hw[((size_t)l * NM + mA) * 4];
    hwB[l] = *(const float4*)&hw[((size_t)l * NM + mA) * 4 + 4];
    hb4[l] = *(const float4*)&hb[(size_t)l * NH + 2 * mA];
  }
  const float4 o4 = *(const float4*)&ow[2 * mA];
  const float2 ob2 = *(const float2*)&ob[mA];
#pragma unroll
  for (int j = 0; j < 8; j++) {
    float a0 = sigf(aA0[j]), a1 = sigf(aA1[j]);
    float b0v = sigf(aB0[j]), b1v = sigf(aB1[j]);
#pragma unroll
    for (int l = 0; l < 2; l++) {
      const float nA0 = sigf(hwA[l].x * a0 + hwA[l].y * a1 + hb4[l].x);
      const float nA1 = sigf(hwA[l].z * a0 + hwA[l].w * a1 + hb4[l].y);
      const float nB0 = sigf(hwB[l].x * b0v + hwB[l].y * b1v + hb4[l].z);
      const float nB1 = sigf(hwB[l].z * b0v + hwB[l].w * b1v + hb4[l].w);
      a0 = nA0; a1 = nA1; b0v = nB0; b1v = nB1;
    }
    const float outA = a0 * o4.x + a1 * o4.y + ob2.x;
    const float outB = b0v * o4.z + b1v * o4.w + ob2.y;
    float2 o2; o2.x = outA; o2.y = outB;
    *(float2*)&out[(size_t)(b0 + bq * 8 + j) * NM + mA] = o2;
  }
}

extern "C" void kernel_launch(void* const* d_in, const int* in_sizes, int n_in,
                              void* d_out, int out_size, void* d_ws, size_t ws_size,
                              hipStream_t stream) {
  const float* x   = (const float*)d_in[0];
  const float* eps = (const float*)d_in[1];
  const float* e1w = (const float*)d_in[2];
  const float* e1b = (const float*)d_in[3];
  const float* e2w = (const float*)d_in[4];
  const float* e2b = (const float*)d_in[5];
  const float* muw = (const float*)d_in[6];
  const float* mub = (const float*)d_in[7];
  const float* lvw = (const float*)d_in[8];
  const float* lvb = (const float*)d_in[9];
  const float* mfw = (const float*)d_in[10];
  const float* mfb = (const float*)d_in[11];
  const float* mhw = (const float*)d_in[12];
  const float* mhb = (const float*)d_in[13];
  const float* mow = (const float*)d_in[14];
  const float* mob = (const float*)d_in[15];
  const float* cfw = (const float*)d_in[16];
  const float* cfb = (const float*)d_in[17];
  const float* chw = (const float*)d_in[18];
  const float* chb = (const float*)d_in[19];
  const float* cow = (const float*)d_in[20];
  const float* cob = (const float*)d_in[21];

  // d_out regions (fp32 elements): out_x [0,16M)B, out_lc [16M,32M)B, mu, lv.
  // bf16/fp32 intermediates overlay dead byte-ranges:
  //   h1 bf16 @ [0,8M)      (dead after enc2; dec-mean overwrites)
  //   xb/h2 bf16 @ [16M,24M) (dead after mulv; dec-cov overwrites)
  //   wcat fp32 @ [24M,26M)  (dead after mulv; dec-cov overwrites)
  char* ob_ = (char*)d_out;
  float* out_x  = (float*)ob_;
  float* out_lc = (float*)(ob_ + (16u << 20));
  float* out_mu = out_x + (size_t)2 * NB * NM;
  float* out_lv = out_mu + (size_t)NB * NZ;
  bf16* h1 = (bf16*)ob_;
  bf16* xb = (bf16*)(ob_ + (16u << 20));
  bf16* h2 = xb;
  float* wcat = (float*)(ob_ + (24u << 20));

  // ws: zpre fp32 512KB + z fp32 256KB = 768KB (round-4-proven budget)
  float* zpre = (float*)d_ws;
  float* z    = (float*)((char*)d_ws + (1u << 19));

  cvt_f32_bf16<<<dim3(4096), 256, 0, stream>>>(x, xb, NB * NM / 4);
  zero_f32<<<dim3(512), 256, 0, stream>>>(zpre, NB * 128);
  wcat_build<<<dim3(512), 256, 0, stream>>>(muw, lvw, wcat);
  gemm_nt<<<dim3(16, 64), 256, 0, stream>>>(xb, e1w, e1b, h1, NM, NM);
  gemm_nt<<<dim3(16, 64), 256, 0, stream>>>(h1, e2w, e2b, h2, NM, NM);
  mulv_mfma<<<dim3(8, 2, 16), 512, 0, stream>>>(h2, wcat, zpre);
  zfin<<<dim3(256), 256, 0, stream>>>(zpre, eps, mub, lvb, out_mu, out_lv, z);
  dec_fused<<<dim3(16, 16, 4), 256, 0, stream>>>(z, mfw, mfb, mhw, mhb, mow, mob, out_x);
  dec_fused<<<dim3(16, 16, 4), 256, 0, stream>>>(z, cfw, cfb, chw, chb, cow, cob, out_lc);
}